// Round 3
// 4329.452 us; speedup vs baseline: 1.0765x; 1.0765x over previous
//
#include <hip/hip_runtime.h>
#include <hip/hip_bf16.h>

typedef __attribute__((ext_vector_type(8))) short bf8;    // 8 bf16 (4 VGPRs)
typedef __attribute__((ext_vector_type(4))) float f32x4;  // MFMA accumulator
typedef __attribute__((ext_vector_type(2))) unsigned int u32x2;  // asm-safe 64-bit payload

#define T_SEQ 1024

__device__ __forceinline__ float sigm(float x) { return 1.f / (1.f + __expf(-x)); }
__device__ __forceinline__ float tanh_(float x) { return 2.f / (1.f + __expf(-2.f * x)) - 1.f; }

__device__ __forceinline__ short bf16s(float x) {
    union { __hip_bfloat16 h; short s; } u;
    u.h = __float2bfloat16(x);
    return u.s;
}

__device__ __forceinline__ bf8 pack_bf8(const float4 a, const float4 b) {
    bf8 r;
    r[0] = bf16s(a.x); r[1] = bf16s(a.y); r[2] = bf16s(a.z); r[3] = bf16s(a.w);
    r[4] = bf16s(b.x); r[5] = bf16s(b.y); r[6] = bf16s(b.z); r[7] = bf16s(b.w);
    return r;
}

// ---- sc1 (device-scope, LLC-coherent) access helpers -----------------------
// gfx950 SC[1:0] scope encoding: sc1 = device scope. Device-scope loads bypass
// L1 AND the (non-device-coherent) per-XCD L2, reading the Infinity Cache;
// device-scope stores write through to it. This is EXACTLY the instruction
// class the round-0 kernel's working agent-scope atomics lowered to — proven to
// propagate across XCDs on this problem. What we do NOT emit (and round 0's
// __hip_atomic release/acquire did): per-step buffer_wbl2 (full dirty-L2
// writeback) and buffer_inv (full L1+L2 invalidate). Those were the ~9.8k
// cycle/step cost and the 3x Xp over-fetch.
__device__ __forceinline__ void store_sc1_b64(void* p, unsigned int lo, unsigned int hi) {
    u32x2 v; v[0] = lo; v[1] = hi;
    asm volatile("global_store_dwordx2 %0, %1, off sc1" :: "v"(p), "v"(v) : "memory");
}
__device__ __forceinline__ void store_sc1_b32(void* p, unsigned int v) {
    asm volatile("global_store_dword %0, %1, off sc1" :: "v"(p), "v"(v) : "memory");
}
__device__ __forceinline__ unsigned int load_sc1_b32(const void* p) {
    unsigned int v;
    asm volatile("global_load_dword %0, %1, off sc1\n"
                 "s_waitcnt vmcnt(0)"
                 : "=v"(v) : "v"(p) : "memory");
    return v;
}
__device__ __forceinline__ bf8 load_sc1_b128(const void* p) {
    bf8 v;  // issued without waitcnt so the 8 frag loads pipeline
    asm volatile("global_load_dwordx4 %0, %1, off sc1" : "=v"(v) : "v"(p) : "memory");
    return v;
}

// ---------------- Phase 0: zero the exchange/flag state (graph-safe) ----------------
__global__ __launch_bounds__(256) void init_kernel(unsigned int* __restrict__ p, int n)
{
    const int i = blockIdx.x * 256 + threadIdx.x;
    if (i < n) p[i] = 0u;
}

// ---------------- Phase 1: Xp = bf16(X @ Wih^T + (bih + bhh))  (both directions) ----------------
// X: fp32 [B*T, 512], row m = b*1024 + t.  Wih: fp32 [1024, 512] (B^T layout).
// Xp: bf16 stored [t][b][1024] -> row (t*64 + b).   (unchanged — verified in round 0)
__global__ __launch_bounds__(256) void xproj_kernel(
    const float* __restrict__ X,
    const float* __restrict__ WihF,
    const float* __restrict__ bihF,
    const float* __restrict__ bhhF,
    const float* __restrict__ WihB,
    const float* __restrict__ bihB,
    const float* __restrict__ bhhB,
    __hip_bfloat16* __restrict__ XpF,
    __hip_bfloat16* __restrict__ XpB)
{
    const int dir = blockIdx.z;
    const float* W  = dir ? WihB : WihF;
    const float* bi = dir ? bihB : bihF;
    const float* bh = dir ? bhhB : bhhF;
    __hip_bfloat16* Xp = dir ? XpB : XpF;

    __shared__ __align__(16) short As[128 * 32];
    __shared__ __align__(16) short Bs[128 * 32];

    const int tid  = threadIdx.x;
    const int lane = tid & 63;
    const int w    = tid >> 6;
    const int quad = lane >> 4;
    const int l16  = lane & 15;
    const int wr   = w >> 1, wc = w & 1;      // 2x2 wave grid, 64x64 per wave

    const int m0 = blockIdx.x * 128;
    const int n0 = blockIdx.y * 128;

    const int srow = tid >> 2;                // staging row within 64-row half
    const int scg  = tid & 3;                 // 8-col group

    f32x4 acc[4][4] = {};

    for (int kk = 0; kk < 512; kk += 32) {
        const float* pa0 = X + (size_t)(m0 + srow)      * 512 + kk + scg * 8;
        const float* pa1 = X + (size_t)(m0 + 64 + srow) * 512 + kk + scg * 8;
        const float* pb0 = W + (size_t)(n0 + srow)      * 512 + kk + scg * 8;
        const float* pb1 = W + (size_t)(n0 + 64 + srow) * 512 + kk + scg * 8;
        bf8 a0 = pack_bf8(*(const float4*)pa0, *(const float4*)(pa0 + 4));
        bf8 a1 = pack_bf8(*(const float4*)pa1, *(const float4*)(pa1 + 4));
        bf8 b0 = pack_bf8(*(const float4*)pb0, *(const float4*)(pb0 + 4));
        bf8 b1 = pack_bf8(*(const float4*)pb1, *(const float4*)(pb1 + 4));
        __syncthreads();  // previous iteration's LDS reads done
        *(bf8*)&As[(srow)      * 32 + scg * 8] = a0;
        *(bf8*)&As[(64 + srow) * 32 + scg * 8] = a1;
        *(bf8*)&Bs[(srow)      * 32 + scg * 8] = b0;
        *(bf8*)&Bs[(64 + srow) * 32 + scg * 8] = b1;
        __syncthreads();

        bf8 af[4], bfr[4];
#pragma unroll
        for (int mt = 0; mt < 4; mt++)
            af[mt] = *(const bf8*)&As[(wr * 64 + mt * 16 + l16) * 32 + quad * 8];
#pragma unroll
        for (int nt = 0; nt < 4; nt++)
            bfr[nt] = *(const bf8*)&Bs[(wc * 64 + nt * 16 + l16) * 32 + quad * 8];
#pragma unroll
        for (int mt = 0; mt < 4; mt++)
#pragma unroll
            for (int nt = 0; nt < 4; nt++)
                acc[mt][nt] = __builtin_amdgcn_mfma_f32_16x16x32_bf16(af[mt], bfr[nt], acc[mt][nt], 0, 0, 0);
    }

#pragma unroll
    for (int nt = 0; nt < 4; nt++) {
        const int n = n0 + wc * 64 + nt * 16 + l16;
        const float bias = bi[n] + bh[n];
#pragma unroll
        for (int mt = 0; mt < 4; mt++) {
#pragma unroll
            for (int r = 0; r < 4; r++) {
                const int m = m0 + wr * 64 + mt * 16 + quad * 4 + r;   // C/D: row=quad*4+r, col=l16
                const int b = m >> 10, t = m & 1023;                    // m = b*1024 + t
                Xp[((size_t)t * 64 + b) * 1024 + n] = __float2bfloat16(acc[mt][nt][r] + bias);
            }
        }
    }
}

// ---------------- Phase 2: recurrence. 32 persistent WGs (16 per direction). ----------------
// WG (dir, s) owns hidden units j = s*16 .. s*16+15 (gate rows g*256 + s*16 + j), all 64 batches.
// Whh slice in registers. h exchanged via hexch in the LLC, double-buffered:
// hexch[buf][dir][slice][64][16] bf16.
// Exchange protocol (all relaxed sc1 = device scope, LLC coherence point; no wbl2/inv):
//   publish: sc1 dwordx2 stores -> per-wave vmcnt(0) drain -> barrier -> tid0 sc1 flag store
//   consume: 16 lanes of wave 0 hard-poll sc1 (no sleep) -> barrier -> sc1 Af loads
__global__ __launch_bounds__(256, 1) void lstm_rec_kernel(
    const __hip_bfloat16* __restrict__ XpF,
    const __hip_bfloat16* __restrict__ XpB,
    const float* __restrict__ WhhF,
    const float* __restrict__ WhhB,
    __hip_bfloat16* __restrict__ hexch,
    int* __restrict__ flags,
    float* __restrict__ out)
{
    const int wg  = blockIdx.x;
    const int dir = wg >> 4;
    const int s   = wg & 15;
    const int tid  = threadIdx.x;
    const int lane = tid & 63;
    const int w    = tid >> 6;       // wave = batch tile (16 batches)
    const int quad = lane >> 4;
    const int l16  = lane & 15;

    const __hip_bfloat16* Xp = dir ? XpB : XpF;
    const float* Whh         = dir ? WhhB : WhhF;
    unsigned int* hexchU     = (unsigned int*)hexch;

    __shared__ unsigned int hstage[512];   // [64 b][16 j] bf16 = 2 KB, dword view

    // Preload Whh slice into registers: Bf[gate][kstep], B-frag layout n=l16, k=quad*8+j.
    bf8 Bf[4][8];
#pragma unroll
    for (int g = 0; g < 4; g++)
#pragma unroll
        for (int k = 0; k < 8; k++) {
            const float* p = Whh + (size_t)(g * 256 + s * 16 + l16) * 256 + k * 32 + quad * 8;
            Bf[g][k] = pack_bf8(*(const float4*)p, *(const float4*)(p + 4));
        }

    float c[4] = {0.f, 0.f, 0.f, 0.f};   // cell state, fp32, never rounded

    // h_0 = 0 and flags = 0 ("h_0 ready") are established by init_kernel (its dirty
    // lines are written back to LLC at its end-of-dispatch release; our sc1 accesses
    // read the LLC directly).

    for (int tau = 0; tau < T_SEQ; tau++) {
        const int t = dir ? (T_SEQ - 1 - tau) : tau;

        // Spin: 16 lanes of wave 0, one flag each (128 B apart), sc1 hard poll.
        // xp loads are issued AFTER the spin so the probe's vmcnt(0) only drains the
        // previous step's 4 out-stores, not 16 in-flight loads.
        if (tid < 16) {
            int* f = &flags[(dir * 16 + tid) * 32];
            while ((int)load_sc1_b32(f) < tau) { }
        }
        __syncthreads();

        // Xp loads (raw bf16 bits; converted and accumulated after the MFMAs).
        unsigned short xpu[4][4];
#pragma unroll
        for (int g = 0; g < 4; g++)
#pragma unroll
            for (int r = 0; r < 4; r++) {
                const int b = w * 16 + quad * 4 + r;
                xpu[g][r] = __builtin_nontemporal_load(
                    (const unsigned short*)&Xp[((size_t)t * 64 + b) * 1024 + g * 256 + s * 16 + l16]);
            }

        // A-frags (h_tau) from hexch buf tau&1: sc1 loads read the LLC directly —
        // no stale L1/L2 possible, so no acquire fence / cache invalidate needed.
        const __hip_bfloat16* hb = hexch + ((size_t)((tau & 1) * 2 + dir) * 16) * 1024;
        bf8 Af[8];
#pragma unroll
        for (int k = 0; k < 8; k++) {
            const int sA = k * 2 + (quad >> 1);          // slice holding k-cols [k*32+quad*8, +8)
            Af[k] = load_sc1_b128(hb + (size_t)sA * 1024 + (w * 16 + l16) * 16 + (quad & 1) * 8);
        }
        asm volatile("s_waitcnt vmcnt(0)" ::: "memory");
        __builtin_amdgcn_sched_barrier(0);   // rule 18: keep MFMAs below the asm waitcnt

        f32x4 acc[4];
        const f32x4 zero = {0.f, 0.f, 0.f, 0.f};
#pragma unroll
        for (int g = 0; g < 4; g++) acc[g] = zero;
#pragma unroll
        for (int k = 0; k < 8; k++)
#pragma unroll
            for (int g = 0; g < 4; g++)
                acc[g] = __builtin_amdgcn_mfma_f32_16x16x32_bf16(Af[k], Bf[g][k], acc[g], 0, 0, 0);

        // Gates; lane holds i,f,g,o for (b = w*16+quad*4+r, j = s*16+l16).
        // xp (Wih*x + bias) is added here, after the recurrent MFMAs.
        float hv[4];
#pragma unroll
        for (int r = 0; r < 4; r++) {
            union { unsigned int u; float f; } cv0, cv1, cv2, cv3;
            cv0.u = (unsigned int)xpu[0][r] << 16;
            cv1.u = (unsigned int)xpu[1][r] << 16;
            cv2.u = (unsigned int)xpu[2][r] << 16;
            cv3.u = (unsigned int)xpu[3][r] << 16;
            const float ig = sigm(acc[0][r] + cv0.f);
            const float fg = sigm(acc[1][r] + cv1.f);
            const float gg = tanh_(acc[2][r] + cv2.f);
            const float og = sigm(acc[3][r] + cv3.f);
            c[r] = fg * c[r] + ig * gg;
            hv[r] = og * tanh_(c[r]);
            const int b = w * 16 + quad * 4 + r;
            ((__hip_bfloat16*)hstage)[b * 16 + l16] = __float2bfloat16(hv[r]);
        }
        __syncthreads();   // hstage complete

        // Publish h_{tau+1}: sc1 write-through dwordx2 per thread into the LLC.
        {
            unsigned int* dst = hexchU + ((size_t)(((tau + 1) & 1) * 2 + dir) * 16 + s) * 512;
            store_sc1_b64(&dst[2 * tid], hstage[2 * tid], hstage[2 * tid + 1]);
        }
        asm volatile("s_waitcnt vmcnt(0)" ::: "memory");   // per-wave drain: data is in LLC
        __syncthreads();                                    // all waves drained
        if (tid == 0)
            store_sc1_b32(&flags[(dir * 16 + s) * 32], (unsigned int)(tau + 1));

        // Output stores off the critical path (drain overlaps next spin).
#pragma unroll
        for (int r = 0; r < 4; r++) {
            const int b = w * 16 + quad * 4 + r;
            __builtin_nontemporal_store(hv[r], &out[((size_t)b * T_SEQ + t) * 512 + dir * 256 + s * 16 + l16]);
        }
    }
}

extern "C" void kernel_launch(void* const* d_in, const int* in_sizes, int n_in,
                              void* d_out, int out_size, void* d_ws, size_t ws_size,
                              hipStream_t stream)
{
    const float* X    = (const float*)d_in[0];
    const float* WihF = (const float*)d_in[1];
    const float* WhhF = (const float*)d_in[2];
    const float* bihF = (const float*)d_in[3];
    const float* bhhF = (const float*)d_in[4];
    const float* WihB = (const float*)d_in[5];
    const float* WhhB = (const float*)d_in[6];
    const float* bihB = (const float*)d_in[7];
    const float* bhhB = (const float*)d_in[8];
    float* out = (float*)d_out;

    char* ws = (char*)d_ws;
    __hip_bfloat16* XpF   = (__hip_bfloat16*)ws;                           // 128 MB
    __hip_bfloat16* XpB   = (__hip_bfloat16*)(ws + 134217728);             // 128 MB
    __hip_bfloat16* hexch = (__hip_bfloat16*)(ws + 268435456);             // 128 KB
    int*            flags = (int*)(ws + 268435456 + 131072);               // 4 KB (128 B spacing)

    // Zero h_0 buffers and flags (0 == "h_0 ready") each replay.
    // Plain kernel (graph-capture-safe; no hipMemset* inside kernel_launch).
    const int initN = (131072 + 4096) / 4;
    init_kernel<<<(initN + 255) / 256, 256, 0, stream>>>((unsigned int*)(ws + 268435456), initN);

    dim3 g1(512, 8, 2);   // 65536/128 m-tiles, 1024/128 n-tiles, 2 directions
    xproj_kernel<<<g1, 256, 0, stream>>>(X, WihF, bihF, bhhF, WihB, bihB, bhhB, XpF, XpB);
    lstm_rec_kernel<<<32, 256, 0, stream>>>(XpF, XpB, WhhF, WhhB, hexch, flags, out);
}